// Round 10
// baseline (367.753 us; speedup 1.0000x reference)
//
#include <hip/hip_runtime.h>
#include <hip/hip_bf16.h>
#include <stdint.h>

typedef unsigned short u16;
typedef __attribute__((ext_vector_type(8))) short bf16x8;
typedef __attribute__((ext_vector_type(4))) float f32x4;

#define LSEQ 2048
#define BSZ  32
#define HDIM 512
#define PDIM 256

__device__ __forceinline__ u16 f2bf(float f) {
  __hip_bfloat16 h = __float2bfloat16(f);
  return *reinterpret_cast<u16*>(&h);
}
__device__ __forceinline__ float bf2f(u16 s) {
  union { uint32_t u; float f; } x; x.u = ((uint32_t)s) << 16; return x.f;
}
__device__ __forceinline__ void gload16(const void* gp, void* lp) {
  __builtin_amdgcn_global_load_lds((const __attribute__((address_space(1))) void*)gp,
                                   (__attribute__((address_space(3))) void*)lp, 16, 0, 0);
}
__device__ __forceinline__ int swz2048(int fid) { return (fid & 7) * 256 + (fid >> 3); }
// fast gelu: x * sigmoid(1.5957691*(x + 0.044715*x^3))  (== tanh-form algebraically)
__device__ __forceinline__ float gelu_fast(float o) {
  float z = 1.595769122f * (o + 0.044715f * o * o * o);
  return o / (1.f + __expf(-z));
}

// ---------- prep1 ----------
__global__ __launch_bounds__(256) void prep1_kernel(
    const float* __restrict__ Lre, const float* __restrict__ Lim,
    const float* __restrict__ lstep, float* __restrict__ lam)
{
  int p = threadIdx.x;
  float delta = expf(lstep[p]);
  float lr = Lre[p], li = Lim[p];
  float mag = expf(lr * delta);
  float ang = li * delta;
  float lbr = mag * cosf(ang);
  float lbi = mag * sinf(ang);
  lam[p] = lbr; lam[256 + p] = lbi;
  float nr = lbr - 1.f, ni = lbi;
  float inv = 1.f / (lr*lr + li*li);
  lam[512 + p] = (nr*lr + ni*li) * inv;
  lam[768 + p] = (ni*lr - nr*li) * inv;
}

// ---------- prep2 ----------
__global__ __launch_bounds__(256) void prep2_kernel(
  const float* __restrict__ Bre, const float* __restrict__ Bim,
  const float* __restrict__ Cre, const float* __restrict__ Cim,
  const float* __restrict__ W1, const float* __restrict__ W2,
  const float* __restrict__ lam,
  u16* __restrict__ Btbu, u16* __restrict__ Ct,
  u16* __restrict__ W1t, u16* __restrict__ W2t)
{
  int id = blockIdx.x * 256 + threadIdx.x;
  int a = id >> 9, b = id & 511;
  if (id < PDIM * HDIM) {
    int p = a, h = b;
    float fre = lam[512 + p], fim = lam[768 + p];
    float br = Bre[p * HDIM + h], bim = Bim[p * HDIM + h];
    Btbu[(size_t)(2*p)   * HDIM + h] = f2bf(fre*br - fim*bim);
    Btbu[(size_t)(2*p+1) * HDIM + h] = f2bf(fre*bim + fim*br);
  }
  {
    int h = a, k = b, c = b >> 1;
    float v = (k & 1) ? -2.f * Cim[h * PDIM + c] : 2.f * Cre[h * PDIM + c];
    Ct[id]  = f2bf(v);
    W1t[id] = f2bf(W1[b * HDIM + a]);
    W2t[id] = f2bf(W2[b * HDIM + a]);
  }
}

// ---------- ln1: grid-stride, params cached in regs ----------
__global__ __launch_bounds__(256) void ln1_kernel(const float* __restrict__ x,
    const float* __restrict__ sc, const float* __restrict__ bi, u16* __restrict__ xn)
{
  const int w = threadIdx.x >> 6, lane = threadIdx.x & 63;
  const int hb = lane * 8;
  float scv[8], biv[8];
  {
    float4 s0 = *(const float4*)(sc + hb), s1 = *(const float4*)(sc + hb + 4);
    float4 b0 = *(const float4*)(bi + hb), b1 = *(const float4*)(bi + hb + 4);
    scv[0]=s0.x;scv[1]=s0.y;scv[2]=s0.z;scv[3]=s0.w;scv[4]=s1.x;scv[5]=s1.y;scv[6]=s1.z;scv[7]=s1.w;
    biv[0]=b0.x;biv[1]=b0.y;biv[2]=b0.z;biv[3]=b0.w;biv[4]=b1.x;biv[5]=b1.y;biv[6]=b1.z;biv[7]=b1.w;
  }
  #pragma unroll
  for (int it = 0; it < 8; it++) {
    const int row = blockIdx.x * 32 + it * 4 + w;
    const size_t base = (size_t)row * HDIM + hb;
    float4 a0 = *(const float4*)(x + base);
    float4 a1 = *(const float4*)(x + base + 4);
    float v[8] = {a0.x,a0.y,a0.z,a0.w,a1.x,a1.y,a1.z,a1.w};
    float s = 0.f, ss = 0.f;
    #pragma unroll
    for (int j = 0; j < 8; j++) { s += v[j]; ss += v[j]*v[j]; }
    #pragma unroll
    for (int o = 32; o; o >>= 1) { s += __shfl_xor(s, o); ss += __shfl_xor(ss, o); }
    float mean = s * (1.f / HDIM);
    float var  = ss * (1.f / HDIM) - mean * mean;
    float rstd = rsqrtf(var + 1e-6f);
    bf16x8 r;
    #pragma unroll
    for (int j = 0; j < 8; j++) {
      float o = (v[j] - mean) * rstd * scv[j] + biv[j];
      r[j] = (short)f2bf(o);
    }
    *(bf16x8*)(xn + base) = r;
  }
}

// ---------- GEMM (single-buffer, measured best) ----------
__global__ __launch_bounds__(256) void gemm_bt_kernel(const u16* __restrict__ A,
    const u16* __restrict__ Bt, u16* __restrict__ C)
{
  __shared__ u16 lA[128 * 64];
  __shared__ u16 lB[128 * 64];
  const int fid = blockIdx.y * 4 + blockIdx.x;
  const int s = swz2048(fid);
  const int m0 = (s >> 2) * 128, n0 = (s & 3) * 128;
  const int tid = threadIdx.x, lane = tid & 63, w = tid >> 6;
  const int wr = w >> 1, wc = w & 1;
  const int srow = lane >> 3, slot = lane & 7;
  const int ksw = ((slot ^ srow) * 8);
  f32x4 zero = {0.f, 0.f, 0.f, 0.f};
  f32x4 acc[4][4];
  #pragma unroll
  for (int i = 0; i < 4; i++)
    #pragma unroll
    for (int j = 0; j < 4; j++) acc[i][j] = zero;

  for (int ks = 0; ks < 8; ++ks) {
    const int kb = ks * 64;
    #pragma unroll
    for (int i = 0; i < 4; i++) {
      const int rb = w * 32 + i * 8;
      gload16(A  + (size_t)(m0 + rb + srow) * HDIM + kb + ksw, &lA[rb * 64]);
      gload16(Bt + (size_t)(n0 + rb + srow) * HDIM + kb + ksw, &lB[rb * 64]);
    }
    __syncthreads();
    const int kk = (lane >> 4) * 8;
    bf16x8 af[4][2], bfv[4][2];
    #pragma unroll
    for (int f = 0; f < 4; f++) {
      const int ra = wr * 64 + f * 16 + (lane & 15);
      const int rb = wc * 64 + f * 16 + (lane & 15);
      const int sa = (ra & 7) << 3, sb = (rb & 7) << 3;
      af[f][0]  = *(const bf16x8*)&lA[ra * 64 + ((kk)      ^ sa)];
      af[f][1]  = *(const bf16x8*)&lA[ra * 64 + ((32 + kk) ^ sa)];
      bfv[f][0] = *(const bf16x8*)&lB[rb * 64 + ((kk)      ^ sb)];
      bfv[f][1] = *(const bf16x8*)&lB[rb * 64 + ((32 + kk) ^ sb)];
    }
    #pragma unroll
    for (int h = 0; h < 2; h++)
      #pragma unroll
      for (int i = 0; i < 4; i++)
        #pragma unroll
        for (int j = 0; j < 4; j++)
          acc[i][j] = __builtin_amdgcn_mfma_f32_16x16x32_bf16(af[i][h], bfv[j][h], acc[i][j], 0, 0, 0);
    __syncthreads();
  }
  #pragma unroll
  for (int i = 0; i < 4; i++) {
    const int row = m0 + wr * 64 + i * 16 + ((lane >> 4) << 2);
    #pragma unroll
    for (int j = 0; j < 4; j++) {
      const int col = n0 + wc * 64 + j * 16 + (lane & 15);
      #pragma unroll
      for (int r = 0; r < 4; r++) C[(size_t)(row + r) * HDIM + col] = f2bf(acc[i][j][r]);
    }
  }
}

// ---------- scan pass A ----------
__global__ __launch_bounds__(256) void scan_a_kernel(const u16* __restrict__ Bu,
   const int* __restrict__ dg, const float* __restrict__ lam,
   float* __restrict__ aAr, float* __restrict__ aAi,
   float* __restrict__ abr, float* __restrict__ abi, float* __restrict__ ac)
{
  const int c = blockIdx.x >> 5;
  const int b = blockIdx.x & 31;
  const int p = threadIdx.x;
  const float lr = lam[p], li = lam[256 + p];
  float Ar = 1.f, Ai = 0.f, br = 0.f, bi = 0.f, ca = 0.f;
  for (int i = 0; i < 32; i++) {
    const int l = c * 32 + i;
    const size_t m = (size_t)(l * BSZ + b);
    uint32_t uv = *(const uint32_t*)(Bu + m * HDIM + 2 * p);
    float ur = bf2f((u16)(uv & 0xffffu));
    float ui = bf2f((u16)(uv >> 16));
    int dd = dg[l * BSZ + b];
    if (dd) { Ar = lr; Ai = li; br = ur; bi = ui; ca = 1.f; }
    else {
      float t1 = lr*Ar - li*Ai, t2 = lr*Ai + li*Ar;
      Ar = t1; Ai = t2;
      float t3 = lr*br - li*bi + ur, t4 = lr*bi + li*br + ui;
      br = t3; bi = t4;
    }
  }
  const int idx = blockIdx.x * 256 + p;
  aAr[idx] = Ar; aAi[idx] = Ai; abr[idx] = br; abi[idx] = bi; ac[idx] = ca;
}

// ---------- scan pass B ----------
__global__ __launch_bounds__(256) void scan_b_kernel(
  const float* __restrict__ h0r, const float* __restrict__ h0i,
  const float* __restrict__ aAr, const float* __restrict__ aAi,
  const float* __restrict__ abr, const float* __restrict__ abi, const float* __restrict__ ac,
  float* __restrict__ prefr, float* __restrict__ prefi,
  float* __restrict__ hro, float* __restrict__ hio)
{
  const int t = blockIdx.x * 256 + threadIdx.x;
  float hr = h0r[t], hi = h0i[t];
  for (int c = 0; c < 64; c++) {
    const int idx = c * 8192 + t;
    prefr[idx] = hr; prefi[idx] = hi;
    float Ar = aAr[idx], Ai = aAi[idx], br = abr[idx], bi = abi[idx], cc = ac[idx];
    float nr = Ar*hr - Ai*hi + br;
    float ni = Ar*hi + Ai*hr + bi;
    hr = (cc != 0.f) ? br : nr;
    hi = (cc != 0.f) ? bi : ni;
  }
  hro[t] = hr; hio[t] = hi;
}

// ---------- scan pass C ----------
__global__ __launch_bounds__(256) void scan_c_kernel(const u16* __restrict__ Bu,
   const int* __restrict__ dg, const float* __restrict__ lam,
   const float* __restrict__ prefr, const float* __restrict__ prefi,
   u16* __restrict__ St)
{
  const int c = blockIdx.x >> 5;
  const int b = blockIdx.x & 31;
  const int p = threadIdx.x;
  const float lr = lam[p], li = lam[256 + p];
  float hr = prefr[blockIdx.x * 256 + p];
  float hi = prefi[blockIdx.x * 256 + p];
  for (int i = 0; i < 32; i++) {
    const int l = c * 32 + i;
    const size_t m = (size_t)(l * BSZ + b);
    uint32_t uv = *(const uint32_t*)(Bu + m * HDIM + 2 * p);
    float ur = bf2f((u16)(uv & 0xffffu));
    float ui = bf2f((u16)(uv >> 16));
    int dd = dg[l * BSZ + b];
    if (dd) { hr = ur; hi = ui; }
    else {
      float t1 = lr*hr - li*hi + ur;
      float t2 = lr*hi + li*hr + ui;
      hr = t1; hi = t2;
    }
    uint32_t wv = (uint32_t)f2bf(hr) | ((uint32_t)f2bf(hi) << 16);
    *(uint32_t*)(St + m * HDIM + 2 * p) = wv;
  }
}

// ---------- ln2: grid-stride; v = y + D*xn, LN, fast-gelu -> g bf16 in place ----------
__global__ __launch_bounds__(256) void ln2_kernel(const u16* __restrict__ Yb,
    u16* __restrict__ xg, const float* __restrict__ Dv,
    const float* __restrict__ sc, const float* __restrict__ bi)
{
  const int w = threadIdx.x >> 6, lane = threadIdx.x & 63;
  const int hb = lane * 8;
  float scv[8], biv[8], dd[8];
  {
    float4 s0 = *(const float4*)(sc + hb), s1 = *(const float4*)(sc + hb + 4);
    float4 b0 = *(const float4*)(bi + hb), b1 = *(const float4*)(bi + hb + 4);
    float4 d0 = *(const float4*)(Dv + hb), d1 = *(const float4*)(Dv + hb + 4);
    scv[0]=s0.x;scv[1]=s0.y;scv[2]=s0.z;scv[3]=s0.w;scv[4]=s1.x;scv[5]=s1.y;scv[6]=s1.z;scv[7]=s1.w;
    biv[0]=b0.x;biv[1]=b0.y;biv[2]=b0.z;biv[3]=b0.w;biv[4]=b1.x;biv[5]=b1.y;biv[6]=b1.z;biv[7]=b1.w;
    dd[0]=d0.x;dd[1]=d0.y;dd[2]=d0.z;dd[3]=d0.w;dd[4]=d1.x;dd[5]=d1.y;dd[6]=d1.z;dd[7]=d1.w;
  }
  #pragma unroll
  for (int it = 0; it < 8; it++) {
    const int row = blockIdx.x * 32 + it * 4 + w;
    const size_t base = (size_t)row * HDIM + hb;
    bf16x8 yv = *(const bf16x8*)(Yb + base);
    bf16x8 xv = *(const bf16x8*)(xg + base);
    float v[8];
    #pragma unroll
    for (int j = 0; j < 8; j++) v[j] = bf2f((u16)yv[j]) + dd[j] * bf2f((u16)xv[j]);
    float s = 0.f, ss = 0.f;
    #pragma unroll
    for (int j = 0; j < 8; j++) { s += v[j]; ss += v[j]*v[j]; }
    #pragma unroll
    for (int o = 32; o; o >>= 1) { s += __shfl_xor(s, o); ss += __shfl_xor(ss, o); }
    float mean = s * (1.f / HDIM);
    float var  = ss * (1.f / HDIM) - mean * mean;
    float rstd = rsqrtf(var + 1e-6f);
    bf16x8 r;
    #pragma unroll
    for (int j = 0; j < 8; j++) {
      float o = (v[j] - mean) * rstd * scv[j] + biv[j];
      r[j] = (short)f2bf(gelu_fast(o));
    }
    *(bf16x8*)(xg + base) = r;
  }
}

// ---------- mlp: 128x64 tile, dbuf prefetch, X-prefetch epilogue, stride-68 repack ----------
__global__ __launch_bounds__(256) void mlp_kernel(const u16* __restrict__ G,
  const u16* __restrict__ W1t, const u16* __restrict__ W2t,
  const float* __restrict__ b1, const float* __restrict__ b2,
  const float* __restrict__ X, float* __restrict__ Out)
{
  __shared__ u16 sh[2][16384];
  const int fid = blockIdx.x;
  const int s = (fid & 7) * 512 + (fid >> 3);
  const int m0 = (s >> 3) * 128, n0 = (s & 7) * 64;
  const int tid = threadIdx.x, lane = tid & 63, w = tid >> 6;
  const int wr = w >> 1, wc = w & 1;
  const int srow = lane >> 3, slot = lane & 7;
  const int ksw = ((slot ^ srow) * 8);
  f32x4 zero = {0.f, 0.f, 0.f, 0.f};
  f32x4 a1[4][2], a2[4][2];
  #pragma unroll
  for (int i = 0; i < 4; i++)
    #pragma unroll
    for (int j = 0; j < 2; j++) { a1[i][j] = zero; a2[i][j] = zero; }

  #pragma unroll
  for (int i = 0; i < 4; i++) {
    const int rb = w * 32 + i * 8;
    gload16(G + (size_t)(m0 + rb + srow) * HDIM + ksw, &sh[0][rb * 64]);
  }
  #pragma unroll
  for (int i = 0; i < 2; i++) {
    const int rb = w * 16 + i * 8;
    gload16(W1t + (size_t)(n0 + rb + srow) * HDIM + ksw, &sh[0][8192  + rb * 64]);
    gload16(W2t + (size_t)(n0 + rb + srow) * HDIM + ksw, &sh[0][12288 + rb * 64]);
  }
  __syncthreads();

  int cur = 0;
  for (int ks = 0; ks < 8; ++ks) {
    if (ks < 7) {
      const int kb = (ks + 1) * 64;
      #pragma unroll
      for (int i = 0; i < 4; i++) {
        const int rb = w * 32 + i * 8;
        gload16(G + (size_t)(m0 + rb + srow) * HDIM + kb + ksw, &sh[cur ^ 1][rb * 64]);
      }
      #pragma unroll
      for (int i = 0; i < 2; i++) {
        const int rb = w * 16 + i * 8;
        gload16(W1t + (size_t)(n0 + rb + srow) * HDIM + kb + ksw, &sh[cur ^ 1][8192  + rb * 64]);
        gload16(W2t + (size_t)(n0 + rb + srow) * HDIM + kb + ksw, &sh[cur ^ 1][12288 + rb * 64]);
      }
    }
    const u16* lG  = sh[cur];
    const u16* lW1 = sh[cur] + 8192;
    const u16* lW2 = sh[cur] + 12288;
    const int kk = (lane >> 4) * 8;
    bf16x8 af[4][2], f1[2][2], f2v[2][2];
    #pragma unroll
    for (int f = 0; f < 4; f++) {
      const int ra = wr * 64 + f * 16 + (lane & 15);
      const int sa = (ra & 7) << 3;
      af[f][0] = *(const bf16x8*)&lG[ra * 64 + ((kk)      ^ sa)];
      af[f][1] = *(const bf16x8*)&lG[ra * 64 + ((32 + kk) ^ sa)];
    }
    #pragma unroll
    for (int j = 0; j < 2; j++) {
      const int rb = wc * 32 + j * 16 + (lane & 15);
      const int sb = (rb & 7) << 3;
      f1[j][0]  = *(const bf16x8*)&lW1[rb * 64 + ((kk)      ^ sb)];
      f1[j][1]  = *(const bf16x8*)&lW1[rb * 64 + ((32 + kk) ^ sb)];
      f2v[j][0] = *(const bf16x8*)&lW2[rb * 64 + ((kk)      ^ sb)];
      f2v[j][1] = *(const bf16x8*)&lW2[rb * 64 + ((32 + kk) ^ sb)];
    }
    #pragma unroll
    for (int h = 0; h < 2; h++)
      #pragma unroll
      for (int i = 0; i < 4; i++)
        #pragma unroll
        for (int j = 0; j < 2; j++) {
          a1[i][j] = __builtin_amdgcn_mfma_f32_16x16x32_bf16(af[i][h], f1[j][h],  a1[i][j], 0, 0, 0);
          a2[i][j] = __builtin_amdgcn_mfma_f32_16x16x32_bf16(af[i][h], f2v[j][h], a2[i][j], 0, 0, 0);
        }
    __syncthreads();
    cur ^= 1;
  }

  // epilogue: (1) issue X loads early; (2) gate -> f32 LDS tile (stride 68 = 16B-aligned rows);
  // (3) barrier; (4) coalesced add + store
  const int erow0 = tid >> 4;              // 0..15
  const int ec4 = (tid & 15) * 4;
  float4 xpre[8];
  #pragma unroll
  for (int sweep = 0; sweep < 8; sweep++) {
    const int row = sweep * 16 + erow0;
    xpre[sweep] = *(const float4*)(X + (size_t)(m0 + row) * HDIM + n0 + ec4);
  }
  float* rep = (float*)&sh[0][0];          // 128 x 68 floats = 34.8 KB (spans both bufs, dead now)
  const int g4 = lane >> 4, l4 = lane & 15;
  #pragma unroll
  for (int i = 0; i < 4; i++) {
    const int rowb = wr * 64 + i * 16 + g4 * 4;
    #pragma unroll
    for (int j = 0; j < 2; j++) {
      const int col = wc * 32 + j * 16 + l4;
      const float bb1 = b1[n0 + col], bb2 = b2[n0 + col];
      #pragma unroll
      for (int r = 0; r < 4; r++) {
        float o1 = a1[i][j][r] + bb1;
        float o2 = a2[i][j][r] + bb2;
        rep[(rowb + r) * 68 + col] = o1 / (1.f + __expf(-o2));
      }
    }
  }
  __syncthreads();
  #pragma unroll
  for (int sweep = 0; sweep < 8; sweep++) {
    const int row = sweep * 16 + erow0;
    float4 v = *(const float4*)&rep[row * 68 + ec4];
    const size_t gi = (size_t)(m0 + row) * HDIM + n0 + ec4;
    v.x += xpre[sweep].x; v.y += xpre[sweep].y; v.z += xpre[sweep].z; v.w += xpre[sweep].w;
    *(float4*)(Out + gi) = v;
  }
}

extern "C" void kernel_launch(void* const* d_in, const int* in_sizes, int n_in,
                              void* d_out, int out_size, void* d_ws, size_t ws_size,
                              hipStream_t stream) {
  (void)in_sizes; (void)n_in; (void)out_size; (void)ws_size;
  const float* h0r = (const float*)d_in[0];
  const float* h0i = (const float*)d_in[1];
  const float* x   = (const float*)d_in[2];
  const float* Lre = (const float*)d_in[3];
  const float* Lim = (const float*)d_in[4];
  const float* Bre = (const float*)d_in[5];
  const float* Bim = (const float*)d_in[6];
  const float* Cre = (const float*)d_in[7];
  const float* Cim = (const float*)d_in[8];
  const float* Dv  = (const float*)d_in[9];
  const float* lst = (const float*)d_in[10];
  const float* nsc = (const float*)d_in[11];
  const float* nbi = (const float*)d_in[12];
  const float* W1  = (const float*)d_in[13];
  const float* b1  = (const float*)d_in[14];
  const float* W2  = (const float*)d_in[15];
  const float* b2  = (const float*)d_in[16];
  const int*   dg  = (const int*)d_in[17];

  char* ws = (char*)d_ws;
  u16* Btbu = (u16*)(ws);
  u16* Ct   = (u16*)(ws + 524288);
  u16* W1t  = (u16*)(ws + 1048576);
  u16* W2t  = (u16*)(ws + 1572864);
  float* lam = (float*)(ws + 2097152);
  u16* xg   = (u16*)(ws + 2101248);
  u16* St   = (u16*)(ws + 2101248 + 67108864);
  char* ag  = ws + 2101248 + 2 * 67108864;
  float* aAr = (float*)(ag);
  float* aAi = (float*)(ag + 2097152);
  float* abr = (float*)(ag + 2 * 2097152);
  float* abi = (float*)(ag + 3 * 2097152);
  float* ac  = (float*)(ag + 4 * 2097152);
  float* prr = (float*)(ag + 5 * 2097152);
  float* pri = (float*)(ag + 6 * 2097152);

  float* out = (float*)d_out;
  u16* Bu16  = (u16*)d_out;
  u16* Yb    = (u16*)d_out + 33554432;
  float* hro = out + 33554432;
  float* hio = out + 33554432 + 8192;

  prep1_kernel<<<1, 256, 0, stream>>>(Lre, Lim, lst, lam);
  prep2_kernel<<<1024, 256, 0, stream>>>(Bre, Bim, Cre, Cim, W1, W2, lam, Btbu, Ct, W1t, W2t);
  ln1_kernel<<<2048, 256, 0, stream>>>(x, nsc, nbi, xg);
  gemm_bt_kernel<<<dim3(4, 512), 256, 0, stream>>>(xg, Btbu, Bu16);
  scan_a_kernel<<<2048, 256, 0, stream>>>(Bu16, dg, lam, aAr, aAi, abr, abi, ac);
  scan_b_kernel<<<32, 256, 0, stream>>>(h0r, h0i, aAr, aAi, abr, abi, ac, prr, pri, hro, hio);
  scan_c_kernel<<<2048, 256, 0, stream>>>(Bu16, dg, lam, prr, pri, St);
  gemm_bt_kernel<<<dim3(4, 512), 256, 0, stream>>>(St, Ct, Yb);
  ln2_kernel<<<2048, 256, 0, stream>>>(Yb, xg, Dv, nsc, nbi);
  mlp_kernel<<<4096, 256, 0, stream>>>(xg, W1t, W2t, b1, b2, x, out);
}

// Round 11
// 328.451 us; speedup vs baseline: 1.1197x; 1.1197x over previous
//
#include <hip/hip_runtime.h>
#include <hip/hip_bf16.h>
#include <stdint.h>

typedef unsigned short u16;
typedef __attribute__((ext_vector_type(8))) short bf16x8;
typedef __attribute__((ext_vector_type(4))) float f32x4;

#define LSEQ 2048
#define BSZ  32
#define HDIM 512
#define PDIM 256

__device__ __forceinline__ u16 f2bf(float f) {
  __hip_bfloat16 h = __float2bfloat16(f);
  return *reinterpret_cast<u16*>(&h);
}
__device__ __forceinline__ float bf2f(u16 s) {
  union { uint32_t u; float f; } x; x.u = ((uint32_t)s) << 16; return x.f;
}
__device__ __forceinline__ void gload16(const void* gp, void* lp) {
  __builtin_amdgcn_global_load_lds((const __attribute__((address_space(1))) void*)gp,
                                   (__attribute__((address_space(3))) void*)lp, 16, 0, 0);
}
__device__ __forceinline__ int swz2048(int fid) { return (fid & 7) * 256 + (fid >> 3); }
// fast gelu: x * sigmoid(1.5957691*(x + 0.044715*x^3))  (== tanh-form algebraically)
__device__ __forceinline__ float gelu_fast(float o) {
  float z = 1.595769122f * (o + 0.044715f * o * o * o);
  return o / (1.f + __expf(-z));
}

// ---------- prep1 ----------
__global__ __launch_bounds__(256) void prep1_kernel(
    const float* __restrict__ Lre, const float* __restrict__ Lim,
    const float* __restrict__ lstep, float* __restrict__ lam)
{
  int p = threadIdx.x;
  float delta = expf(lstep[p]);
  float lr = Lre[p], li = Lim[p];
  float mag = expf(lr * delta);
  float ang = li * delta;
  float lbr = mag * cosf(ang);
  float lbi = mag * sinf(ang);
  lam[p] = lbr; lam[256 + p] = lbi;
  float nr = lbr - 1.f, ni = lbi;
  float inv = 1.f / (lr*lr + li*li);
  lam[512 + p] = (nr*lr + ni*li) * inv;
  lam[768 + p] = (ni*lr - nr*li) * inv;
}

// ---------- prep2 ----------
__global__ __launch_bounds__(256) void prep2_kernel(
  const float* __restrict__ Bre, const float* __restrict__ Bim,
  const float* __restrict__ Cre, const float* __restrict__ Cim,
  const float* __restrict__ W1, const float* __restrict__ W2,
  const float* __restrict__ lam,
  u16* __restrict__ Btbu, u16* __restrict__ Ct,
  u16* __restrict__ W1t, u16* __restrict__ W2t)
{
  int id = blockIdx.x * 256 + threadIdx.x;
  int a = id >> 9, b = id & 511;
  if (id < PDIM * HDIM) {
    int p = a, h = b;
    float fre = lam[512 + p], fim = lam[768 + p];
    float br = Bre[p * HDIM + h], bim = Bim[p * HDIM + h];
    Btbu[(size_t)(2*p)   * HDIM + h] = f2bf(fre*br - fim*bim);
    Btbu[(size_t)(2*p+1) * HDIM + h] = f2bf(fre*bim + fim*br);
  }
  {
    int h = a, k = b, c = b >> 1;
    float v = (k & 1) ? -2.f * Cim[h * PDIM + c] : 2.f * Cre[h * PDIM + c];
    Ct[id]  = f2bf(v);
    W1t[id] = f2bf(W1[b * HDIM + a]);
    W2t[id] = f2bf(W2[b * HDIM + a]);
  }
}

// ---------- ln1: grid-stride, params cached in regs ----------
__global__ __launch_bounds__(256) void ln1_kernel(const float* __restrict__ x,
    const float* __restrict__ sc, const float* __restrict__ bi, u16* __restrict__ xn)
{
  const int w = threadIdx.x >> 6, lane = threadIdx.x & 63;
  const int hb = lane * 8;
  float scv[8], biv[8];
  {
    float4 s0 = *(const float4*)(sc + hb), s1 = *(const float4*)(sc + hb + 4);
    float4 b0 = *(const float4*)(bi + hb), b1 = *(const float4*)(bi + hb + 4);
    scv[0]=s0.x;scv[1]=s0.y;scv[2]=s0.z;scv[3]=s0.w;scv[4]=s1.x;scv[5]=s1.y;scv[6]=s1.z;scv[7]=s1.w;
    biv[0]=b0.x;biv[1]=b0.y;biv[2]=b0.z;biv[3]=b0.w;biv[4]=b1.x;biv[5]=b1.y;biv[6]=b1.z;biv[7]=b1.w;
  }
  #pragma unroll
  for (int it = 0; it < 8; it++) {
    const int row = blockIdx.x * 32 + it * 4 + w;
    const size_t base = (size_t)row * HDIM + hb;
    float4 a0 = *(const float4*)(x + base);
    float4 a1 = *(const float4*)(x + base + 4);
    float v[8] = {a0.x,a0.y,a0.z,a0.w,a1.x,a1.y,a1.z,a1.w};
    float s = 0.f, ss = 0.f;
    #pragma unroll
    for (int j = 0; j < 8; j++) { s += v[j]; ss += v[j]*v[j]; }
    #pragma unroll
    for (int o = 32; o; o >>= 1) { s += __shfl_xor(s, o); ss += __shfl_xor(ss, o); }
    float mean = s * (1.f / HDIM);
    float var  = ss * (1.f / HDIM) - mean * mean;
    float rstd = rsqrtf(var + 1e-6f);
    bf16x8 r;
    #pragma unroll
    for (int j = 0; j < 8; j++) {
      float o = (v[j] - mean) * rstd * scv[j] + biv[j];
      r[j] = (short)f2bf(o);
    }
    *(bf16x8*)(xn + base) = r;
  }
}

// ---------- GEMM (single-buffer, measured best) ----------
__global__ __launch_bounds__(256) void gemm_bt_kernel(const u16* __restrict__ A,
    const u16* __restrict__ Bt, u16* __restrict__ C)
{
  __shared__ u16 lA[128 * 64];
  __shared__ u16 lB[128 * 64];
  const int fid = blockIdx.y * 4 + blockIdx.x;
  const int s = swz2048(fid);
  const int m0 = (s >> 2) * 128, n0 = (s & 3) * 128;
  const int tid = threadIdx.x, lane = tid & 63, w = tid >> 6;
  const int wr = w >> 1, wc = w & 1;
  const int srow = lane >> 3, slot = lane & 7;
  const int ksw = ((slot ^ srow) * 8);
  f32x4 zero = {0.f, 0.f, 0.f, 0.f};
  f32x4 acc[4][4];
  #pragma unroll
  for (int i = 0; i < 4; i++)
    #pragma unroll
    for (int j = 0; j < 4; j++) acc[i][j] = zero;

  for (int ks = 0; ks < 8; ++ks) {
    const int kb = ks * 64;
    #pragma unroll
    for (int i = 0; i < 4; i++) {
      const int rb = w * 32 + i * 8;
      gload16(A  + (size_t)(m0 + rb + srow) * HDIM + kb + ksw, &lA[rb * 64]);
      gload16(Bt + (size_t)(n0 + rb + srow) * HDIM + kb + ksw, &lB[rb * 64]);
    }
    __syncthreads();
    const int kk = (lane >> 4) * 8;
    bf16x8 af[4][2], bfv[4][2];
    #pragma unroll
    for (int f = 0; f < 4; f++) {
      const int ra = wr * 64 + f * 16 + (lane & 15);
      const int rb = wc * 64 + f * 16 + (lane & 15);
      const int sa = (ra & 7) << 3, sb = (rb & 7) << 3;
      af[f][0]  = *(const bf16x8*)&lA[ra * 64 + ((kk)      ^ sa)];
      af[f][1]  = *(const bf16x8*)&lA[ra * 64 + ((32 + kk) ^ sa)];
      bfv[f][0] = *(const bf16x8*)&lB[rb * 64 + ((kk)      ^ sb)];
      bfv[f][1] = *(const bf16x8*)&lB[rb * 64 + ((32 + kk) ^ sb)];
    }
    #pragma unroll
    for (int h = 0; h < 2; h++)
      #pragma unroll
      for (int i = 0; i < 4; i++)
        #pragma unroll
        for (int j = 0; j < 4; j++)
          acc[i][j] = __builtin_amdgcn_mfma_f32_16x16x32_bf16(af[i][h], bfv[j][h], acc[i][j], 0, 0, 0);
    __syncthreads();
  }
  #pragma unroll
  for (int i = 0; i < 4; i++) {
    const int row = m0 + wr * 64 + i * 16 + ((lane >> 4) << 2);
    #pragma unroll
    for (int j = 0; j < 4; j++) {
      const int col = n0 + wc * 64 + j * 16 + (lane & 15);
      #pragma unroll
      for (int r = 0; r < 4; r++) C[(size_t)(row + r) * HDIM + col] = f2bf(acc[i][j][r]);
    }
  }
}

// ---------- scan pass A ----------
__global__ __launch_bounds__(256) void scan_a_kernel(const u16* __restrict__ Bu,
   const int* __restrict__ dg, const float* __restrict__ lam,
   float* __restrict__ aAr, float* __restrict__ aAi,
   float* __restrict__ abr, float* __restrict__ abi, float* __restrict__ ac)
{
  const int c = blockIdx.x >> 5;
  const int b = blockIdx.x & 31;
  const int p = threadIdx.x;
  const float lr = lam[p], li = lam[256 + p];
  float Ar = 1.f, Ai = 0.f, br = 0.f, bi = 0.f, ca = 0.f;
  for (int i = 0; i < 32; i++) {
    const int l = c * 32 + i;
    const size_t m = (size_t)(l * BSZ + b);
    uint32_t uv = *(const uint32_t*)(Bu + m * HDIM + 2 * p);
    float ur = bf2f((u16)(uv & 0xffffu));
    float ui = bf2f((u16)(uv >> 16));
    int dd = dg[l * BSZ + b];
    if (dd) { Ar = lr; Ai = li; br = ur; bi = ui; ca = 1.f; }
    else {
      float t1 = lr*Ar - li*Ai, t2 = lr*Ai + li*Ar;
      Ar = t1; Ai = t2;
      float t3 = lr*br - li*bi + ur, t4 = lr*bi + li*br + ui;
      br = t3; bi = t4;
    }
  }
  const int idx = blockIdx.x * 256 + p;
  aAr[idx] = Ar; aAi[idx] = Ai; abr[idx] = br; abi[idx] = bi; ac[idx] = ca;
}

// ---------- scan pass B ----------
__global__ __launch_bounds__(256) void scan_b_kernel(
  const float* __restrict__ h0r, const float* __restrict__ h0i,
  const float* __restrict__ aAr, const float* __restrict__ aAi,
  const float* __restrict__ abr, const float* __restrict__ abi, const float* __restrict__ ac,
  float* __restrict__ prefr, float* __restrict__ prefi,
  float* __restrict__ hro, float* __restrict__ hio)
{
  const int t = blockIdx.x * 256 + threadIdx.x;
  float hr = h0r[t], hi = h0i[t];
  for (int c = 0; c < 64; c++) {
    const int idx = c * 8192 + t;
    prefr[idx] = hr; prefi[idx] = hi;
    float Ar = aAr[idx], Ai = aAi[idx], br = abr[idx], bi = abi[idx], cc = ac[idx];
    float nr = Ar*hr - Ai*hi + br;
    float ni = Ar*hi + Ai*hr + bi;
    hr = (cc != 0.f) ? br : nr;
    hi = (cc != 0.f) ? bi : ni;
  }
  hro[t] = hr; hio[t] = hi;
}

// ---------- scan pass C ----------
__global__ __launch_bounds__(256) void scan_c_kernel(const u16* __restrict__ Bu,
   const int* __restrict__ dg, const float* __restrict__ lam,
   const float* __restrict__ prefr, const float* __restrict__ prefi,
   u16* __restrict__ St)
{
  const int c = blockIdx.x >> 5;
  const int b = blockIdx.x & 31;
  const int p = threadIdx.x;
  const float lr = lam[p], li = lam[256 + p];
  float hr = prefr[blockIdx.x * 256 + p];
  float hi = prefi[blockIdx.x * 256 + p];
  for (int i = 0; i < 32; i++) {
    const int l = c * 32 + i;
    const size_t m = (size_t)(l * BSZ + b);
    uint32_t uv = *(const uint32_t*)(Bu + m * HDIM + 2 * p);
    float ur = bf2f((u16)(uv & 0xffffu));
    float ui = bf2f((u16)(uv >> 16));
    int dd = dg[l * BSZ + b];
    if (dd) { hr = ur; hi = ui; }
    else {
      float t1 = lr*hr - li*hi + ur;
      float t2 = lr*hi + li*hr + ui;
      hr = t1; hi = t2;
    }
    uint32_t wv = (uint32_t)f2bf(hr) | ((uint32_t)f2bf(hi) << 16);
    *(uint32_t*)(St + m * HDIM + 2 * p) = wv;
  }
}

// ---------- ln2: grid-stride; v = y + D*xn, LN, fast-gelu -> g bf16 in place ----------
__global__ __launch_bounds__(256) void ln2_kernel(const u16* __restrict__ Yb,
    u16* __restrict__ xg, const float* __restrict__ Dv,
    const float* __restrict__ sc, const float* __restrict__ bi)
{
  const int w = threadIdx.x >> 6, lane = threadIdx.x & 63;
  const int hb = lane * 8;
  float scv[8], biv[8], dd[8];
  {
    float4 s0 = *(const float4*)(sc + hb), s1 = *(const float4*)(sc + hb + 4);
    float4 b0 = *(const float4*)(bi + hb), b1 = *(const float4*)(bi + hb + 4);
    float4 d0 = *(const float4*)(Dv + hb), d1 = *(const float4*)(Dv + hb + 4);
    scv[0]=s0.x;scv[1]=s0.y;scv[2]=s0.z;scv[3]=s0.w;scv[4]=s1.x;scv[5]=s1.y;scv[6]=s1.z;scv[7]=s1.w;
    biv[0]=b0.x;biv[1]=b0.y;biv[2]=b0.z;biv[3]=b0.w;biv[4]=b1.x;biv[5]=b1.y;biv[6]=b1.z;biv[7]=b1.w;
    dd[0]=d0.x;dd[1]=d0.y;dd[2]=d0.z;dd[3]=d0.w;dd[4]=d1.x;dd[5]=d1.y;dd[6]=d1.z;dd[7]=d1.w;
  }
  #pragma unroll
  for (int it = 0; it < 8; it++) {
    const int row = blockIdx.x * 32 + it * 4 + w;
    const size_t base = (size_t)row * HDIM + hb;
    bf16x8 yv = *(const bf16x8*)(Yb + base);
    bf16x8 xv = *(const bf16x8*)(xg + base);
    float v[8];
    #pragma unroll
    for (int j = 0; j < 8; j++) v[j] = bf2f((u16)yv[j]) + dd[j] * bf2f((u16)xv[j]);
    float s = 0.f, ss = 0.f;
    #pragma unroll
    for (int j = 0; j < 8; j++) { s += v[j]; ss += v[j]*v[j]; }
    #pragma unroll
    for (int o = 32; o; o >>= 1) { s += __shfl_xor(s, o); ss += __shfl_xor(ss, o); }
    float mean = s * (1.f / HDIM);
    float var  = ss * (1.f / HDIM) - mean * mean;
    float rstd = rsqrtf(var + 1e-6f);
    bf16x8 r;
    #pragma unroll
    for (int j = 0; j < 8; j++) {
      float o = (v[j] - mean) * rstd * scv[j] + biv[j];
      r[j] = (short)f2bf(gelu_fast(o));
    }
    *(bf16x8*)(xg + base) = r;
  }
}

// ---------- mlp: 128x64 tile, dbuf prefetch, stride-66 repack (R9-best) + setprio ----------
__global__ __launch_bounds__(256) void mlp_kernel(const u16* __restrict__ G,
  const u16* __restrict__ W1t, const u16* __restrict__ W2t,
  const float* __restrict__ b1, const float* __restrict__ b2,
  const float* __restrict__ X, float* __restrict__ Out)
{
  __shared__ u16 sh[2][16384];
  const int fid = blockIdx.x;
  const int s = (fid & 7) * 512 + (fid >> 3);
  const int m0 = (s >> 3) * 128, n0 = (s & 7) * 64;
  const int tid = threadIdx.x, lane = tid & 63, w = tid >> 6;
  const int wr = w >> 1, wc = w & 1;
  const int srow = lane >> 3, slot = lane & 7;
  const int ksw = ((slot ^ srow) * 8);
  f32x4 zero = {0.f, 0.f, 0.f, 0.f};
  f32x4 a1[4][2], a2[4][2];
  #pragma unroll
  for (int i = 0; i < 4; i++)
    #pragma unroll
    for (int j = 0; j < 2; j++) { a1[i][j] = zero; a2[i][j] = zero; }

  #pragma unroll
  for (int i = 0; i < 4; i++) {
    const int rb = w * 32 + i * 8;
    gload16(G + (size_t)(m0 + rb + srow) * HDIM + ksw, &sh[0][rb * 64]);
  }
  #pragma unroll
  for (int i = 0; i < 2; i++) {
    const int rb = w * 16 + i * 8;
    gload16(W1t + (size_t)(n0 + rb + srow) * HDIM + ksw, &sh[0][8192  + rb * 64]);
    gload16(W2t + (size_t)(n0 + rb + srow) * HDIM + ksw, &sh[0][12288 + rb * 64]);
  }
  __syncthreads();

  int cur = 0;
  for (int ks = 0; ks < 8; ++ks) {
    if (ks < 7) {
      const int kb = (ks + 1) * 64;
      #pragma unroll
      for (int i = 0; i < 4; i++) {
        const int rb = w * 32 + i * 8;
        gload16(G + (size_t)(m0 + rb + srow) * HDIM + kb + ksw, &sh[cur ^ 1][rb * 64]);
      }
      #pragma unroll
      for (int i = 0; i < 2; i++) {
        const int rb = w * 16 + i * 8;
        gload16(W1t + (size_t)(n0 + rb + srow) * HDIM + kb + ksw, &sh[cur ^ 1][8192  + rb * 64]);
        gload16(W2t + (size_t)(n0 + rb + srow) * HDIM + kb + ksw, &sh[cur ^ 1][12288 + rb * 64]);
      }
    }
    const u16* lG  = sh[cur];
    const u16* lW1 = sh[cur] + 8192;
    const u16* lW2 = sh[cur] + 12288;
    const int kk = (lane >> 4) * 8;
    bf16x8 af[4][2], f1[2][2], f2v[2][2];
    #pragma unroll
    for (int f = 0; f < 4; f++) {
      const int ra = wr * 64 + f * 16 + (lane & 15);
      const int sa = (ra & 7) << 3;
      af[f][0] = *(const bf16x8*)&lG[ra * 64 + ((kk)      ^ sa)];
      af[f][1] = *(const bf16x8*)&lG[ra * 64 + ((32 + kk) ^ sa)];
    }
    #pragma unroll
    for (int j = 0; j < 2; j++) {
      const int rb = wc * 32 + j * 16 + (lane & 15);
      const int sb = (rb & 7) << 3;
      f1[j][0]  = *(const bf16x8*)&lW1[rb * 64 + ((kk)      ^ sb)];
      f1[j][1]  = *(const bf16x8*)&lW1[rb * 64 + ((32 + kk) ^ sb)];
      f2v[j][0] = *(const bf16x8*)&lW2[rb * 64 + ((kk)      ^ sb)];
      f2v[j][1] = *(const bf16x8*)&lW2[rb * 64 + ((32 + kk) ^ sb)];
    }
    __builtin_amdgcn_s_setprio(1);   // T5: favor MFMA-phase waves vs other block's staging
    #pragma unroll
    for (int h = 0; h < 2; h++)
      #pragma unroll
      for (int i = 0; i < 4; i++)
        #pragma unroll
        for (int j = 0; j < 2; j++) {
          a1[i][j] = __builtin_amdgcn_mfma_f32_16x16x32_bf16(af[i][h], f1[j][h],  a1[i][j], 0, 0, 0);
          a2[i][j] = __builtin_amdgcn_mfma_f32_16x16x32_bf16(af[i][h], f2v[j][h], a2[i][j], 0, 0, 0);
        }
    __builtin_amdgcn_s_setprio(0);
    __syncthreads();
    cur ^= 1;
  }

  // epilogue (R9-best): gate -> f32 LDS tile stride 66 (2-way banks), barrier, coalesced X+store
  float* rep = (float*)&sh[0][0];
  const int g4 = lane >> 4, l4 = lane & 15;
  #pragma unroll
  for (int i = 0; i < 4; i++) {
    const int rowb = wr * 64 + i * 16 + g4 * 4;
    #pragma unroll
    for (int j = 0; j < 2; j++) {
      const int col = wc * 32 + j * 16 + l4;
      const float bb1 = b1[n0 + col], bb2 = b2[n0 + col];
      #pragma unroll
      for (int r = 0; r < 4; r++) {
        float o1 = a1[i][j][r] + bb1;
        float o2 = a2[i][j][r] + bb2;
        rep[(rowb + r) * 66 + col] = o1 / (1.f + __expf(-o2));
      }
    }
  }
  __syncthreads();
  #pragma unroll
  for (int sweep = 0; sweep < 8; sweep++) {
    const int row = sweep * 16 + (tid >> 4);
    const int c4 = (tid & 15) * 4;
    float4 v = *(const float4*)&rep[row * 66 + c4];
    const size_t gi = (size_t)(m0 + row) * HDIM + n0 + c4;
    const float4 xv = *(const float4*)(X + gi);
    v.x += xv.x; v.y += xv.y; v.z += xv.z; v.w += xv.w;
    *(float4*)(Out + gi) = v;
  }
}

extern "C" void kernel_launch(void* const* d_in, const int* in_sizes, int n_in,
                              void* d_out, int out_size, void* d_ws, size_t ws_size,
                              hipStream_t stream) {
  (void)in_sizes; (void)n_in; (void)out_size; (void)ws_size;
  const float* h0r = (const float*)d_in[0];
  const float* h0i = (const float*)d_in[1];
  const float* x   = (const float*)d_in[2];
  const float* Lre = (const float*)d_in[3];
  const float* Lim = (const float*)d_in[4];
  const float* Bre = (const float*)d_in[5];
  const float* Bim = (const float*)d_in[6];
  const float* Cre = (const float*)d_in[7];
  const float* Cim = (const float*)d_in[8];
  const float* Dv  = (const float*)d_in[9];
  const float* lst = (const float*)d_in[10];
  const float* nsc = (const float*)d_in[11];
  const float* nbi = (const float*)d_in[12];
  const float* W1  = (const float*)d_in[13];
  const float* b1  = (const float*)d_in[14];
  const float* W2  = (const float*)d_in[15];
  const float* b2  = (const float*)d_in[16];
  const int*   dg  = (const int*)d_in[17];

  char* ws = (char*)d_ws;
  u16* Btbu = (u16*)(ws);
  u16* Ct   = (u16*)(ws + 524288);
  u16* W1t  = (u16*)(ws + 1048576);
  u16* W2t  = (u16*)(ws + 1572864);
  float* lam = (float*)(ws + 2097152);
  u16* xg   = (u16*)(ws + 2101248);
  u16* St   = (u16*)(ws + 2101248 + 67108864);
  char* ag  = ws + 2101248 + 2 * 67108864;
  float* aAr = (float*)(ag);
  float* aAi = (float*)(ag + 2097152);
  float* abr = (float*)(ag + 2 * 2097152);
  float* abi = (float*)(ag + 3 * 2097152);
  float* ac  = (float*)(ag + 4 * 2097152);
  float* prr = (float*)(ag + 5 * 2097152);
  float* pri = (float*)(ag + 6 * 2097152);

  float* out = (float*)d_out;
  u16* Bu16  = (u16*)d_out;
  u16* Yb    = (u16*)d_out + 33554432;
  float* hro = out + 33554432;
  float* hio = out + 33554432 + 8192;

  prep1_kernel<<<1, 256, 0, stream>>>(Lre, Lim, lst, lam);
  prep2_kernel<<<1024, 256, 0, stream>>>(Bre, Bim, Cre, Cim, W1, W2, lam, Btbu, Ct, W1t, W2t);
  ln1_kernel<<<2048, 256, 0, stream>>>(x, nsc, nbi, xg);
  gemm_bt_kernel<<<dim3(4, 512), 256, 0, stream>>>(xg, Btbu, Bu16);
  scan_a_kernel<<<2048, 256, 0, stream>>>(Bu16, dg, lam, aAr, aAi, abr, abi, ac);
  scan_b_kernel<<<32, 256, 0, stream>>>(h0r, h0i, aAr, aAi, abr, abi, ac, prr, pri, hro, hio);
  scan_c_kernel<<<2048, 256, 0, stream>>>(Bu16, dg, lam, prr, pri, St);
  gemm_bt_kernel<<<dim3(4, 512), 256, 0, stream>>>(St, Ct, Yb);
  ln2_kernel<<<2048, 256, 0, stream>>>(Yb, xg, Dv, nsc, nbi);
  mlp_kernel<<<4096, 256, 0, stream>>>(xg, W1t, W2t, b1, b2, x, out);
}